// Round 1
// baseline (2485.115 us; speedup 1.0000x reference)
//
#include <hip/hip_runtime.h>
#include <math.h>

// Text2SemanticDecoder single-token decode, MI355X round 2.
// R2 change: the 123-launch structure (5 kernels x 24 layers) was
// launch/latency-bound at 5.6% of the 505MB/6.3TB/s roofline. Collapsed into
// ONE persistent cooperative kernel (256 blocks x 256 thr = 1 block/CU) with a
// device-scope counter barrier; 4 grid syncs per layer + logits + final = 97.
// All stages repartitioned so all 256 CUs stream coalesced weight slices.

#define LNUM 24
#define TPOS 2048
#define DMOD 512
#define HNUM 16
#define VOC  1025
#define TYN  512
#define FFD  2048
#define DHD  32
#define NBLK 256
#define NTHR 256

#define INV_SQRT_DH 0.17677669529663687f

// ---------------- helpers ----------------

__device__ __forceinline__ unsigned rotl32(unsigned x, int d) {
    return (x << d) | (x >> (32 - d));
}

// threefry2x32, PARTITIONABLE scheme: key=(0,42), ctr=(0,i), bits=o0^o1
__device__ float threefry_normal(int i) {
    unsigned c0 = 0u;
    unsigned c1 = (unsigned)i;
    unsigned ks[3];
    ks[0] = 0u; ks[1] = 42u; ks[2] = 0x1BD11BDAu ^ ks[0] ^ ks[1];
    unsigned x0 = c0 + ks[0];
    unsigned x1 = c1 + ks[1];
    const int r0[4] = {13, 15, 26, 6};
    const int r1[4] = {17, 29, 16, 24};
    #pragma unroll
    for (int g = 0; g < 5; ++g) {
        const int* rr = (g & 1) ? r1 : r0;
        #pragma unroll
        for (int j = 0; j < 4; ++j) {
            x0 += x1; x1 = rotl32(x1, rr[j]); x1 ^= x0;
        }
        x0 += ks[(g + 1) % 3];
        x1 += ks[(g + 2) % 3] + (unsigned)(g + 1);
    }
    unsigned bits = x0 ^ x1;
    float u01 = __uint_as_float((bits >> 9) | 0x3f800000u) - 1.0f;
    const float lo = -0.99999994f;
    float u = u01 * (1.0f - lo) + lo;
    u = fmaxf(lo, u);
    float w = -log1pf(-u * u);
    float pp;
    if (w < 5.0f) {
        w = w - 2.5f;
        pp = 2.81022636e-08f;
        pp = fmaf(pp, w, 3.43273939e-07f);
        pp = fmaf(pp, w, -3.5233877e-06f);
        pp = fmaf(pp, w, -4.39150654e-06f);
        pp = fmaf(pp, w, 0.00021858087f);
        pp = fmaf(pp, w, -0.00125372503f);
        pp = fmaf(pp, w, -0.00417768164f);
        pp = fmaf(pp, w, 0.246640727f);
        pp = fmaf(pp, w, 1.50140941f);
    } else {
        w = sqrtf(w) - 3.0f;
        pp = -0.000200214257f;
        pp = fmaf(pp, w, 0.000100950558f);
        pp = fmaf(pp, w, 0.00134934322f);
        pp = fmaf(pp, w, -0.00367342844f);
        pp = fmaf(pp, w, 0.00573950773f);
        pp = fmaf(pp, w, -0.0076224613f);
        pp = fmaf(pp, w, 0.00943887047f);
        pp = fmaf(pp, w, 1.00167406f);
        pp = fmaf(pp, w, 2.83297682f);
    }
    return 1.4142135623730951f * pp * u;  // sqrt(2)*erfinv(u)
}

__global__ void zero_kernel(float* p, int n) {
    int i = blockIdx.x * blockDim.x + threadIdx.x;
    if (i < n) p[i] = 0.0f;
}

__device__ __forceinline__ float wave_red_sum(float v) {
    #pragma unroll
    for (int o = 32; o; o >>= 1) v += __shfl_xor(v, o, 64);
    return v;
}
__device__ __forceinline__ float wave_red_max(float v) {
    #pragma unroll
    for (int o = 32; o; o >>= 1) v = fmaxf(v, __shfl_xor(v, o, 64));
    return v;
}
__device__ __forceinline__ float block_sum(float v, float* red8, int tid) {
    v = wave_red_sum(v);
    __syncthreads();
    if ((tid & 63) == 0) red8[tid >> 6] = v;
    __syncthreads();
    return red8[0] + red8[1] + red8[2] + red8[3];
}
__device__ __forceinline__ float block_max(float v, float* red8, int tid) {
    v = wave_red_max(v);
    __syncthreads();
    if ((tid & 63) == 0) red8[tid >> 6] = v;
    __syncthreads();
    return fmaxf(fmaxf(red8[0], red8[1]), fmaxf(red8[2], red8[3]));
}

// grid barrier: monotonic counter (zeroed per launch by zero_kernel).
// release = __threadfence before arrival (wbl2), acquire = __threadfence after
// spin (inv) -> cross-XCD L2 coherence per Guideline 16.
__device__ __forceinline__ void gsync(unsigned* ctr, unsigned& target, int tid) {
    __syncthreads();
    target += NBLK;
    if (tid == 0) {
        __threadfence();
        __hip_atomic_fetch_add(ctr, 1u, __ATOMIC_RELAXED, __HIP_MEMORY_SCOPE_AGENT);
        while (__hip_atomic_load(ctr, __ATOMIC_RELAXED, __HIP_MEMORY_SCOPE_AGENT) < target)
            __builtin_amdgcn_s_sleep(1);
        __threadfence();
    }
    __syncthreads();
}

// LN(u) -> xs[512] in LDS; all 256 threads participate.
__device__ __forceinline__ void ln_into(const float* __restrict__ u, const float* __restrict__ g,
                                        const float* __restrict__ b, float* xs, float* red8, int tid) {
    float a = u[tid], c = u[tid + 256];
    float s1 = block_sum(a + c, red8, tid);
    float s2 = block_sum(a * a + c * c, red8, tid);
    float mu = s1 * (1.0f / DMOD);
    float var = s2 * (1.0f / DMOD) - mu * mu;
    float rstd = rsqrtf(var + 1e-5f);
    xs[tid]       = (a - mu) * rstd * g[tid] + b[tid];
    xs[tid + 256] = (c - mu) * rstd * g[tid + 256] + b[tid + 256];
    __syncthreads();
}

// layer-0 input: tok_emb[last] + alpha*pe(pos=512)
__device__ __forceinline__ void x0_into(const int* __restrict__ y, const float* __restrict__ tokemb,
                                        const float* __restrict__ alpha, float* xs, int tid) {
    int tok = y[TYN - 1];
    #pragma unroll
    for (int r = 0; r < 2; ++r) {
        int d = tid + r * 256;
        float e = tokemb[(size_t)tok * DMOD + d];
        int base = d & ~1;
        float div = expf(-(float)base * (logf(10000.0f) / (float)DMOD));
        float ang = 512.0f * div;
        float pe = (d & 1) ? cosf(ang) : sinf(ang);
        xs[d] = e + alpha[0] * pe;
    }
    __syncthreads();
}

// ---------------- the persistent kernel ----------------

__global__ __launch_bounds__(NTHR) void decode_kernel(
    const int* __restrict__ y, const float* __restrict__ kcache, const float* __restrict__ vcache,
    const float* __restrict__ tokemb, const float* __restrict__ alpha,
    const float* __restrict__ qkvw, const float* __restrict__ qkvbias,
    const float* __restrict__ outw, const float* __restrict__ outb,
    const float* __restrict__ ln1g, const float* __restrict__ ln1b,
    const float* __restrict__ ff1w, const float* __restrict__ ff1b,
    const float* __restrict__ ff2w, const float* __restrict__ ff2b,
    const float* __restrict__ ln2g, const float* __restrict__ ln2b,
    const float* __restrict__ predw, float* __restrict__ out, float* ws)
{
    __shared__ float xs[DMOD];
    __shared__ float red8[8];
    __shared__ float ps[NTHR];
    __shared__ float vred[NTHR];
    __shared__ float qs[DHD];
    __shared__ float os[DHD];
    __shared__ float hs[16];
    __shared__ float redt[NTHR];
    // final stage
    __shared__ float lg[VOC];
    __shared__ float sel[VOC];
    __shared__ unsigned char flagc[VOC];
    __shared__ float rv[4];
    __shared__ int   ri[4];

    int tid = threadIdx.x, blk = blockIdx.x;

    unsigned* ctr   = (unsigned*)ws;                 // ws[0] zeroed each launch
    float* qkv_all  = ws + 16;                       // 24*1536 (atomic, zeroed)
    float* u1_all   = qkv_all + LNUM * 3 * DMOD;     // 24*512  (atomic, zeroed)
    float* u2_all   = u1_all + LNUM * DMOD;          // 24*512  (atomic, zeroed)
    float* attnp    = u2_all + LNUM * DMOD;          // 16*16*34 (direct write, reused per layer)
    float* logits   = attnp + HNUM * 16 * 34;        // 1025   (direct write)
    unsigned target = 0;

    float* kout = out + 1026;
    float* vout = out + 1026 + (size_t)LNUM * DMOD;

    for (int l = 0; l < LNUM; ++l) {
        const float* u_prev = (l == 0) ? (const float*)0 : (u2_all + (size_t)(l - 1) * DMOD);
        const float* gp = (l == 0) ? (const float*)0 : (ln2g + (size_t)(l - 1) * DMOD);
        const float* bp = (l == 0) ? (const float*)0 : (ln2b + (size_t)(l - 1) * DMOD);
        float* qkvb = qkv_all + (size_t)l * 3 * DMOD;

        // ---- stage 1: qkv = LN(x_prev) @ W + b; 192 blocks = 12 colblk x 16 ksplit ----
        if (blk < 192) {
            if (l == 0) x0_into(y, tokemb, alpha, xs, tid);
            else        ln_into(u_prev, gp, bp, xs, red8, tid);
            int cb = blk >> 4, ks = blk & 15;
            int col = cb * 128 + (tid & 127);
            int r0 = ks * 32 + (tid >> 7) * 16;
            const float* wp = qkvw + (size_t)l * DMOD * 3 * DMOD + (size_t)r0 * (3 * DMOD) + col;
            float acc = 0.f;
            #pragma unroll
            for (int i = 0; i < 16; ++i) acc += xs[r0 + i] * wp[(size_t)i * (3 * DMOD)];
            if (ks == 0 && tid < 128) acc += qkvbias[(size_t)l * 3 * DMOD + col];
            atomicAdd(&qkvb[col], acc);
        }
        gsync(ctr, target, tid);

        // ---- stage 2: attention partials; 256 blocks = 16 heads x 16 chunks(128 pos) ----
        {
            int h = blk >> 4, c = blk & 15;
            if (tid < DHD) qs[tid] = qkvb[h * DHD + tid];
            __syncthreads();
            float sc = -INFINITY;
            if (tid < 128) {
                int pos = c * 128 + tid;
                const float* kp = kcache + (size_t)l * TPOS * DMOD + (size_t)pos * DMOD + h * DHD;
                float s = 0.f;
                #pragma unroll
                for (int d = 0; d < DHD; ++d) s += qs[d] * kp[d];
                sc = s * INV_SQRT_DH;
            } else if (tid == 128 && c == 15) {
                // new token (position 2048): k from qkv
                const float* kp = qkvb + DMOD + h * DHD;
                float s = 0.f;
                #pragma unroll
                for (int d = 0; d < DHD; ++d) s += qs[d] * kp[d];
                sc = s * INV_SQRT_DH;
            }
            float m = block_max(sc, red8, tid);
            float p = expf(sc - m);     // inactive threads: expf(-inf)=0
            ps[tid] = p;
            float lsum = block_sum(p, red8, tid);
            // PV: tid = pg*32 + d
            int d = tid & (DHD - 1), pg = tid >> 5;
            const float* vbase = vcache + (size_t)l * TPOS * DMOD + (size_t)(c * 128) * DMOD + h * DHD + d;
            float acc = 0.f;
            #pragma unroll
            for (int it = 0; it < 16; ++it) {
                int p2 = pg + it * 8;
                acc += ps[p2] * vbase[(size_t)p2 * DMOD];
            }
            if (c == 15 && pg == 0) acc += ps[128] * qkvb[2 * DMOD + h * DHD + d];
            vred[tid] = acc;
            __syncthreads();
            float* ap = attnp + (size_t)(h * 16 + c) * 34;
            if (tid < DHD) {
                float a = 0.f;
                #pragma unroll
                for (int g = 0; g < 8; ++g) a += vred[g * DHD + tid];
                ap[2 + tid] = a;
            }
            if (tid == 0) { ap[0] = m; ap[1] = lsum; }
            if (c == 0 && tid < DHD) {
                kout[(size_t)l * DMOD + h * DHD + tid] = qkvb[DMOD + h * DHD + tid];
                vout[(size_t)l * DMOD + h * DHD + tid] = qkvb[2 * DMOD + h * DHD + tid];
            }
        }
        gsync(ctr, target, tid);

        // ---- stage 3: combine + out-proj + residual -> u1; 256 blocks = 16 h x 16 colgrp ----
        {
            int h = blk >> 4, cg = blk & 15;
            if (h == 0) {
                if (l == 0) x0_into(y, tokemb, alpha, xs, tid);
                else        ln_into(u_prev, gp, bp, xs, red8, tid);
            }
            const float* apb = attnp + (size_t)(h * 16) * 34;
            float M = -INFINITY;
            #pragma unroll
            for (int c = 0; c < 16; ++c) M = fmaxf(M, apb[c * 34]);
            float lsum = 0.f;
            #pragma unroll
            for (int c = 0; c < 16; ++c) lsum += apb[c * 34 + 1] * expf(apb[c * 34] - M);
            if (tid < DHD) {
                float acc = 0.f;
                #pragma unroll
                for (int c = 0; c < 16; ++c) acc += apb[c * 34 + 2 + tid] * expf(apb[c * 34] - M);
                os[tid] = acc / lsum;
            }
            __syncthreads();
            if (tid < 32) {
                int col = cg * 32 + tid;
                const float* wp = outw + (size_t)l * DMOD * DMOD + (size_t)(h * DHD) * DMOD + col;
                float acc2 = 0.f;
                #pragma unroll
                for (int d = 0; d < DHD; ++d) acc2 += os[d] * wp[(size_t)d * DMOD];
                if (h == 0) acc2 += xs[col] + outb[(size_t)l * DMOD + col];
                atomicAdd(&u1_all[(size_t)l * DMOD + col], acc2);
            }
        }
        gsync(ctr, target, tid);

        // ---- stage 4: x1 = LN(u1); u2 += x1 + relu(x1@W1+b1)@W2 + b2; 128 blocks x 16 j ----
        if (blk < 128) {
            float* u1l = u1_all + (size_t)l * DMOD;
            float* u2l = u2_all + (size_t)l * DMOD;
            ln_into(u1l, ln1g + (size_t)l * DMOD, ln1b + (size_t)l * DMOD, xs, red8, tid);
            int j0 = blk * 16;
            int jj = tid & 15, dg = tid >> 4;
            const float* wp = ff1w + (size_t)l * DMOD * FFD + (size_t)(dg * 32) * FFD + j0 + jj;
            float acc = 0.f;
            #pragma unroll
            for (int i = 0; i < 32; ++i) acc += xs[dg * 32 + i] * wp[(size_t)i * FFD];
            redt[tid] = acc;
            __syncthreads();
            for (int off = 128; off >= 16; off >>= 1) {
                if (tid < off) redt[tid] += redt[tid + off];
                __syncthreads();
            }
            if (tid < 16) hs[tid] = fmaxf(redt[tid] + ff1b[(size_t)l * FFD + j0 + tid], 0.f);
            __syncthreads();
            const float* w2p = ff2w + (size_t)l * FFD * DMOD + (size_t)j0 * DMOD;
            #pragma unroll
            for (int half = 0; half < 2; ++half) {
                int col = tid + half * 256;
                float a2 = 0.f;
                #pragma unroll
                for (int j = 0; j < 16; ++j) a2 += hs[j] * w2p[(size_t)j * DMOD + col];
                if (blk == 0) a2 += xs[col] + ff2b[(size_t)l * DMOD + col];
                atomicAdd(&u2l[col], a2);
            }
        }
        gsync(ctr, target, tid);
    }

    // ---- logits = LN(u2_last) @ pred_w; 256 blocks x 4 cols (+col 1024 on blk 255) ----
    {
        const float* u2L = u2_all + (size_t)(LNUM - 1) * DMOD;
        ln_into(u2L, ln2g + (size_t)(LNUM - 1) * DMOD, ln2b + (size_t)(LNUM - 1) * DMOD, xs, red8, tid);
        int c = tid & 3, dg = tid >> 2;
        int col = blk * 4 + c;
        const float* wp = predw + (size_t)(dg * 8) * VOC + col;
        float acc = 0.f;
        #pragma unroll
        for (int i = 0; i < 8; ++i) acc += xs[dg * 8 + i] * wp[(size_t)i * VOC];
        redt[tid] = acc;
        __syncthreads();
        for (int off = 128; off >= 4; off >>= 1) {
            if (tid < off) redt[tid] += redt[tid + off];
            __syncthreads();
        }
        if (tid < 4) logits[blk * 4 + tid] = redt[tid];
        if (blk == 255) {
            __syncthreads();
            float a2 = xs[tid * 2] * predw[(size_t)(tid * 2) * VOC + 1024]
                     + xs[tid * 2 + 1] * predw[(size_t)(tid * 2 + 1) * VOC + 1024];
            redt[tid] = a2;
            __syncthreads();
            for (int off = 128; off >= 1; off >>= 1) {
                if (tid < off) redt[tid] += redt[tid + off];
                __syncthreads();
            }
            if (tid == 0) logits[1024] = redt[0];
        }
    }
    gsync(ctr, target, tid);

    // ---- final: penalty + top-15 + softmax + noise argmax; block 0 only ----
    if (blk != 0) return;

    for (int i = tid; i < VOC; i += NTHR) { lg[i] = logits[i]; flagc[i] = 0; }
    __syncthreads();
    for (int j = tid; j < TYN; j += NTHR) flagc[y[j]] = 1;
    __syncthreads();
    for (int i = tid; i < VOC; i += NTHR) {
        if (flagc[i]) { float v = lg[i]; lg[i] = (v < 0.0f) ? v * 1.35f : v / 1.35f; }
    }
    __syncthreads();
    for (int i = tid; i < VOC; i += NTHR) sel[i] = lg[i];
    __syncthreads();

    float v0 = 0.f, v15 = 0.f;
    for (int k = 0; k < 15; ++k) {
        float bv = -INFINITY; int bi = VOC + 1;
        for (int i = tid; i < VOC; i += NTHR) {
            float v = sel[i];
            if (v > bv) { bv = v; bi = i; }
        }
        #pragma unroll
        for (int o = 32; o; o >>= 1) {
            float v2 = __shfl_xor(bv, o, 64);
            int i2 = __shfl_xor(bi, o, 64);
            if (v2 > bv || (v2 == bv && i2 < bi)) { bv = v2; bi = i2; }
        }
        if ((tid & 63) == 0) { rv[tid >> 6] = bv; ri[tid >> 6] = bi; }
        __syncthreads();
        if (tid == 0) {
            for (int w = 1; w < 4; ++w)
                if (rv[w] > rv[0] || (rv[w] == rv[0] && ri[w] < ri[0])) { rv[0] = rv[w]; ri[0] = ri[w]; }
            sel[ri[0]] = -INFINITY;
        }
        __syncthreads();
        if (k == 0)  v0  = rv[0];
        if (k == 14) v15 = rv[0];
        __syncthreads();
    }

    float se = 0.f;
    for (int i = tid; i < VOC; i += NTHR) {
        float v = lg[i];
        if (!(v < v15)) se += expf(v - v0);
    }
    se = wave_red_sum(se);
    if ((tid & 63) == 0) rv[tid >> 6] = se;
    __syncthreads();
    float total = rv[0] + rv[1] + rv[2] + rv[3];
    __syncthreads();

    float bv = -INFINITY; int bi = VOC + 1;
    for (int i = tid; i < VOC; i += NTHR) {
        float v = lg[i];
        float pr = (v < v15) ? 0.0f : expf(v - v0) / total;
        out[i] = pr;
        float r = pr / threefry_normal(i);
        if (r > bv || (r == bv && i < bi)) { bv = r; bi = i; }
    }
    #pragma unroll
    for (int o = 32; o; o >>= 1) {
        float v2 = __shfl_xor(bv, o, 64);
        int i2 = __shfl_xor(bi, o, 64);
        if (v2 > bv || (v2 == bv && i2 < bi)) { bv = v2; bi = i2; }
    }
    __syncthreads();
    if ((tid & 63) == 0) { rv[tid >> 6] = bv; ri[tid >> 6] = bi; }
    __syncthreads();
    if (tid == 0) {
        for (int w = 1; w < 4; ++w)
            if (rv[w] > rv[0] || (rv[w] == rv[0] && ri[w] < ri[0])) { rv[0] = rv[w]; ri[0] = ri[w]; }
        out[VOC] = (float)ri[0];
    }
}

// ---------------- host ----------------

extern "C" void kernel_launch(void* const* d_in, const int* in_sizes, int n_in,
                              void* d_out, int out_size, void* d_ws, size_t ws_size,
                              hipStream_t stream) {
    const int*   y      = (const int*)d_in[0];
    const float* kcache = (const float*)d_in[1];
    const float* vcache = (const float*)d_in[2];
    const float* tokemb = (const float*)d_in[4];
    const float* alpha  = (const float*)d_in[5];
    const float* qkvw   = (const float*)d_in[6];
    const float* qkvb   = (const float*)d_in[7];
    const float* outw   = (const float*)d_in[8];
    const float* outb   = (const float*)d_in[9];
    const float* ln1g   = (const float*)d_in[10];
    const float* ln1b   = (const float*)d_in[11];
    const float* ff1w   = (const float*)d_in[12];
    const float* ff1b   = (const float*)d_in[13];
    const float* ff2w   = (const float*)d_in[14];
    const float* ff2b   = (const float*)d_in[15];
    const float* ln2g   = (const float*)d_in[16];
    const float* ln2b   = (const float*)d_in[17];
    const float* predw  = (const float*)d_in[18];
    float* outp = (float*)d_out;
    float* wsf  = (float*)d_ws;

    // ws layout (floats): ctr[16] | qkv[24*1536] | u1[24*512] | u2[24*512]
    //                     | attnp[16*16*34] | logits[1025]
    // the atomic-accumulated prefix (incl. counter) must be zeroed per launch:
    const int ZN = 16 + LNUM * 3 * DMOD + LNUM * DMOD + LNUM * DMOD;  // 61456
    zero_kernel<<<(ZN + 255) / 256, 256, 0, stream>>>(wsf, ZN);

    void* args[] = {
        (void*)&y, (void*)&kcache, (void*)&vcache, (void*)&tokemb, (void*)&alpha,
        (void*)&qkvw, (void*)&qkvb, (void*)&outw, (void*)&outb,
        (void*)&ln1g, (void*)&ln1b, (void*)&ff1w, (void*)&ff1b,
        (void*)&ff2w, (void*)&ff2b, (void*)&ln2g, (void*)&ln2b,
        (void*)&predw, (void*)&outp, (void*)&wsf
    };
    hipLaunchCooperativeKernel((const void*)decode_kernel, dim3(NBLK), dim3(NTHR),
                               args, 0, stream);
}

// Round 2
// 968.459 us; speedup vs baseline: 2.5661x; 2.5661x over previous
//
#include <hip/hip_runtime.h>
#include <math.h>

// Text2SemanticDecoder single-token decode, MI355X round 3.
// R2: one cooperative kernel, but gsync used ONE counter word: 256 atomic RMWs
// + 255 spin-readers on the same address (serialized at coherence point) plus
// __threadfence (L2 wb+inv) => ~22us/barrier, 2168us total, GPU idle (VALU 0.8%).
// R3: contention-free barrier — per-block arrive slot (1 writer) polled by one
// dedicated thread of block 0 (1 reader), per-block go slot (1 writer, 1 reader).
// No __threadfence: intermediates via atomicAdd / AGENT-scope atomic ld/st which
// bypass XCD-local L2 (coherent per m20; R2's counter proved it); __syncthreads
// already drains vmcnt(0) per wave, giving release ordering for free.

#define LNUM 24
#define TPOS 2048
#define DMOD 512
#define HNUM 16
#define VOC  1025
#define TYN  512
#define FFD  2048
#define DHD  32
#define NBLK 256
#define NTHR 256

#define INV_SQRT_DH 0.17677669529663687f

// ---------------- helpers ----------------

__device__ __forceinline__ unsigned rotl32(unsigned x, int d) {
    return (x << d) | (x >> (32 - d));
}

// threefry2x32, PARTITIONABLE scheme: key=(0,42), ctr=(0,i), bits=o0^o1
__device__ float threefry_normal(int i) {
    unsigned c0 = 0u;
    unsigned c1 = (unsigned)i;
    unsigned ks[3];
    ks[0] = 0u; ks[1] = 42u; ks[2] = 0x1BD11BDAu ^ ks[0] ^ ks[1];
    unsigned x0 = c0 + ks[0];
    unsigned x1 = c1 + ks[1];
    const int r0[4] = {13, 15, 26, 6};
    const int r1[4] = {17, 29, 16, 24};
    #pragma unroll
    for (int g = 0; g < 5; ++g) {
        const int* rr = (g & 1) ? r1 : r0;
        #pragma unroll
        for (int j = 0; j < 4; ++j) {
            x0 += x1; x1 = rotl32(x1, rr[j]); x1 ^= x0;
        }
        x0 += ks[(g + 1) % 3];
        x1 += ks[(g + 2) % 3] + (unsigned)(g + 1);
    }
    unsigned bits = x0 ^ x1;
    float u01 = __uint_as_float((bits >> 9) | 0x3f800000u) - 1.0f;
    const float lo = -0.99999994f;
    float u = u01 * (1.0f - lo) + lo;
    u = fmaxf(lo, u);
    float w = -log1pf(-u * u);
    float pp;
    if (w < 5.0f) {
        w = w - 2.5f;
        pp = 2.81022636e-08f;
        pp = fmaf(pp, w, 3.43273939e-07f);
        pp = fmaf(pp, w, -3.5233877e-06f);
        pp = fmaf(pp, w, -4.39150654e-06f);
        pp = fmaf(pp, w, 0.00021858087f);
        pp = fmaf(pp, w, -0.00125372503f);
        pp = fmaf(pp, w, -0.00417768164f);
        pp = fmaf(pp, w, 0.246640727f);
        pp = fmaf(pp, w, 1.50140941f);
    } else {
        w = sqrtf(w) - 3.0f;
        pp = -0.000200214257f;
        pp = fmaf(pp, w, 0.000100950558f);
        pp = fmaf(pp, w, 0.00134934322f);
        pp = fmaf(pp, w, -0.00367342844f);
        pp = fmaf(pp, w, 0.00573950773f);
        pp = fmaf(pp, w, -0.0076224613f);
        pp = fmaf(pp, w, 0.00943887047f);
        pp = fmaf(pp, w, 1.00167406f);
        pp = fmaf(pp, w, 2.83297682f);
    }
    return 1.4142135623730951f * pp * u;  // sqrt(2)*erfinv(u)
}

__global__ void zero_kernel(float* p, int n) {
    int i = blockIdx.x * blockDim.x + threadIdx.x;
    if (i < n) p[i] = 0.0f;
}

__device__ __forceinline__ float wave_red_sum(float v) {
    #pragma unroll
    for (int o = 32; o; o >>= 1) v += __shfl_xor(v, o, 64);
    return v;
}
__device__ __forceinline__ float wave_red_max(float v) {
    #pragma unroll
    for (int o = 32; o; o >>= 1) v = fmaxf(v, __shfl_xor(v, o, 64));
    return v;
}
__device__ __forceinline__ float block_sum(float v, float* red8, int tid) {
    v = wave_red_sum(v);
    __syncthreads();
    if ((tid & 63) == 0) red8[tid >> 6] = v;
    __syncthreads();
    return red8[0] + red8[1] + red8[2] + red8[3];
}
__device__ __forceinline__ float block_max(float v, float* red8, int tid) {
    v = wave_red_max(v);
    __syncthreads();
    if ((tid & 63) == 0) red8[tid >> 6] = v;
    __syncthreads();
    return fmaxf(fmaxf(red8[0], red8[1]), fmaxf(red8[2], red8[3]));
}

// agent-scope (cross-XCD coherent) load/store for small intermediates
__device__ __forceinline__ float gloadf(const float* p) {
    return __hip_atomic_load((float*)p, __ATOMIC_RELAXED, __HIP_MEMORY_SCOPE_AGENT);
}
__device__ __forceinline__ void gstoref(float* p, float v) {
    __hip_atomic_store(p, v, __ATOMIC_RELAXED, __HIP_MEMORY_SCOPE_AGENT);
}

// Contention-free grid barrier. Every slot has exactly ONE writer and ONE
// reader. __syncthreads() before/inside provides the vmcnt(0) drain (release)
// for all waves of the block; atomicAdd/AGENT ops bypass local L2, so no
// threadfence (L2 wb/inv) is needed.
__device__ __forceinline__ void gsync(unsigned* goB, unsigned* arr,
                                      unsigned& epoch, int tid, int blk) {
    __syncthreads();               // all waves' vmem drained here
    ++epoch;
    if (blk == 0) {
        if (tid > 0) {             // thread t polls block t's arrive slot
            while (__hip_atomic_load(&arr[tid * 16], __ATOMIC_RELAXED,
                                     __HIP_MEMORY_SCOPE_AGENT) < epoch)
                __builtin_amdgcn_s_sleep(1);
        }
        __syncthreads();
        if (tid > 0)               // thread t releases block t's go slot
            __hip_atomic_store(&goB[tid * 16], epoch, __ATOMIC_RELAXED,
                               __HIP_MEMORY_SCOPE_AGENT);
    } else {
        if (tid == 0) {
            __hip_atomic_store(&arr[blk * 16], epoch, __ATOMIC_RELAXED,
                               __HIP_MEMORY_SCOPE_AGENT);
            while (__hip_atomic_load(&goB[blk * 16], __ATOMIC_RELAXED,
                                     __HIP_MEMORY_SCOPE_AGENT) < epoch)
                __builtin_amdgcn_s_sleep(1);
        }
        __syncthreads();
    }
}

// LN(u) -> xs[512] in LDS; u is a cross-stage intermediate (agent loads).
__device__ __forceinline__ void ln_into(const float* __restrict__ u, const float* __restrict__ g,
                                        const float* __restrict__ b, float* xs, float* red8, int tid) {
    float a = gloadf(u + tid), c = gloadf(u + tid + 256);
    float s1 = block_sum(a + c, red8, tid);
    float s2 = block_sum(a * a + c * c, red8, tid);
    float mu = s1 * (1.0f / DMOD);
    float var = s2 * (1.0f / DMOD) - mu * mu;
    float rstd = rsqrtf(var + 1e-5f);
    xs[tid]       = (a - mu) * rstd * g[tid] + b[tid];
    xs[tid + 256] = (c - mu) * rstd * g[tid + 256] + b[tid + 256];
    __syncthreads();
}

// layer-0 input: tok_emb[last] + alpha*pe(pos=512)  (pure kernel inputs)
__device__ __forceinline__ void x0_into(const int* __restrict__ y, const float* __restrict__ tokemb,
                                        const float* __restrict__ alpha, float* xs, int tid) {
    int tok = y[TYN - 1];
    #pragma unroll
    for (int r = 0; r < 2; ++r) {
        int d = tid + r * 256;
        float e = tokemb[(size_t)tok * DMOD + d];
        int base = d & ~1;
        float div = expf(-(float)base * (logf(10000.0f) / (float)DMOD));
        float ang = 512.0f * div;
        float pe = (d & 1) ? cosf(ang) : sinf(ang);
        xs[d] = e + alpha[0] * pe;
    }
    __syncthreads();
}

// ---------------- the persistent kernel ----------------

__global__ __launch_bounds__(NTHR) void decode_kernel(
    const int* __restrict__ y, const float* __restrict__ kcache, const float* __restrict__ vcache,
    const float* __restrict__ tokemb, const float* __restrict__ alpha,
    const float* __restrict__ qkvw, const float* __restrict__ qkvbias,
    const float* __restrict__ outw, const float* __restrict__ outb,
    const float* __restrict__ ln1g, const float* __restrict__ ln1b,
    const float* __restrict__ ff1w, const float* __restrict__ ff1b,
    const float* __restrict__ ff2w, const float* __restrict__ ff2b,
    const float* __restrict__ ln2g, const float* __restrict__ ln2b,
    const float* __restrict__ predw, float* __restrict__ out, float* ws)
{
    __shared__ float xs[DMOD];
    __shared__ float red8[8];
    __shared__ float ps[NTHR];
    __shared__ float vred[NTHR];
    __shared__ float qs[DHD];
    __shared__ float os[DHD];
    __shared__ float hs[16];
    __shared__ float redt[NTHR];
    // final stage
    __shared__ float lg[VOC];
    __shared__ float sel[VOC];
    __shared__ unsigned char flagc[VOC];
    __shared__ float rv[4];
    __shared__ int   ri[4];

    int tid = threadIdx.x, blk = blockIdx.x;

    // ws layout (floats):
    //   [0,4096)      go slots   (256 x 16-word stride)
    //   [4096,8192)   arrive slots
    //   [8192,...)    qkv[24*1536] | u1[24*512] | u2[24*512] | attnp[16*16*34] | logits[1025]
    unsigned* goB   = (unsigned*)ws;
    unsigned* arr   = (unsigned*)ws + 4096;
    float* qkv_all  = ws + 8192;
    float* u1_all   = qkv_all + LNUM * 3 * DMOD;
    float* u2_all   = u1_all + LNUM * DMOD;
    float* attnp    = u2_all + LNUM * DMOD;
    float* logits   = attnp + HNUM * 16 * 34;
    unsigned epoch  = 0;

    float* kout = out + 1026;
    float* vout = out + 1026 + (size_t)LNUM * DMOD;

    for (int l = 0; l < LNUM; ++l) {
        const float* u_prev = (l == 0) ? (const float*)0 : (u2_all + (size_t)(l - 1) * DMOD);
        const float* gp = (l == 0) ? (const float*)0 : (ln2g + (size_t)(l - 1) * DMOD);
        const float* bp = (l == 0) ? (const float*)0 : (ln2b + (size_t)(l - 1) * DMOD);
        float* qkvb = qkv_all + (size_t)l * 3 * DMOD;

        // ---- stage 1: qkv = LN(x_prev) @ W + b; 192 blocks = 12 colblk x 16 ksplit ----
        if (blk < 192) {
            if (l == 0) x0_into(y, tokemb, alpha, xs, tid);
            else        ln_into(u_prev, gp, bp, xs, red8, tid);
            int cb = blk >> 4, ks = blk & 15;
            int col = cb * 128 + (tid & 127);
            int r0 = ks * 32 + (tid >> 7) * 16;
            const float* wp = qkvw + (size_t)l * DMOD * 3 * DMOD + (size_t)r0 * (3 * DMOD) + col;
            float acc = 0.f;
            #pragma unroll
            for (int i = 0; i < 16; ++i) acc += xs[r0 + i] * wp[(size_t)i * (3 * DMOD)];
            if (ks == 0 && tid < 128) acc += qkvbias[(size_t)l * 3 * DMOD + col];
            atomicAdd(&qkvb[col], acc);
        }
        gsync(goB, arr, epoch, tid, blk);

        // ---- stage 2: attention partials; 256 blocks = 16 heads x 16 chunks(128 pos) ----
        {
            int h = blk >> 4, c = blk & 15;
            if (tid < DHD) qs[tid] = gloadf(&qkvb[h * DHD + tid]);
            __syncthreads();
            float sc = -INFINITY;
            if (tid < 128) {
                int pos = c * 128 + tid;
                const float* kp = kcache + (size_t)l * TPOS * DMOD + (size_t)pos * DMOD + h * DHD;
                float s = 0.f;
                #pragma unroll
                for (int d = 0; d < DHD; ++d) s += qs[d] * kp[d];
                sc = s * INV_SQRT_DH;
            } else if (tid == 128 && c == 15) {
                // new token (position 2048): k from qkv
                float s = 0.f;
                #pragma unroll
                for (int d = 0; d < DHD; ++d) s += qs[d] * gloadf(&qkvb[DMOD + h * DHD + d]);
                sc = s * INV_SQRT_DH;
            }
            float m = block_max(sc, red8, tid);
            float p = expf(sc - m);     // inactive threads: expf(-inf)=0
            ps[tid] = p;
            float lsum = block_sum(p, red8, tid);
            // PV: tid = pg*32 + d
            int d = tid & (DHD - 1), pg = tid >> 5;
            const float* vbase = vcache + (size_t)l * TPOS * DMOD + (size_t)(c * 128) * DMOD + h * DHD + d;
            float acc = 0.f;
            #pragma unroll
            for (int it = 0; it < 16; ++it) {
                int p2 = pg + it * 8;
                acc += ps[p2] * vbase[(size_t)p2 * DMOD];
            }
            if (c == 15 && pg == 0) acc += ps[128] * gloadf(&qkvb[2 * DMOD + h * DHD + d]);
            vred[tid] = acc;
            __syncthreads();
            float* ap = attnp + (size_t)(h * 16 + c) * 34;
            if (tid < DHD) {
                float a = 0.f;
                #pragma unroll
                for (int g = 0; g < 8; ++g) a += vred[g * DHD + tid];
                gstoref(&ap[2 + tid], a);
            }
            if (tid == 0) { gstoref(&ap[0], m); gstoref(&ap[1], lsum); }
            if (c == 0 && tid < DHD) {
                kout[(size_t)l * DMOD + h * DHD + tid] = gloadf(&qkvb[DMOD + h * DHD + tid]);
                vout[(size_t)l * DMOD + h * DHD + tid] = gloadf(&qkvb[2 * DMOD + h * DHD + tid]);
            }
        }
        gsync(goB, arr, epoch, tid, blk);

        // ---- stage 3: combine + out-proj + residual -> u1; 256 blocks = 16 h x 16 colgrp ----
        {
            int h = blk >> 4, cg = blk & 15;
            if (h == 0) {
                if (l == 0) x0_into(y, tokemb, alpha, xs, tid);
                else        ln_into(u_prev, gp, bp, xs, red8, tid);
            }
            const float* apb = attnp + (size_t)(h * 16) * 34;
            if (tid < DHD) {
                float M = -INFINITY;
                #pragma unroll
                for (int c = 0; c < 16; ++c) M = fmaxf(M, gloadf(&apb[c * 34]));
                float lsum = 0.f, acc = 0.f;
                #pragma unroll
                for (int c = 0; c < 16; ++c) {
                    float f = expf(gloadf(&apb[c * 34]) - M);
                    lsum += gloadf(&apb[c * 34 + 1]) * f;
                    acc  += gloadf(&apb[c * 34 + 2 + tid]) * f;
                }
                os[tid] = acc / lsum;
            }
            __syncthreads();
            if (tid < 32) {
                int col = cg * 32 + tid;
                const float* wp = outw + (size_t)l * DMOD * DMOD + (size_t)(h * DHD) * DMOD + col;
                float acc2 = 0.f;
                #pragma unroll
                for (int d = 0; d < DHD; ++d) acc2 += os[d] * wp[(size_t)d * DMOD];
                if (h == 0) acc2 += xs[col] + outb[(size_t)l * DMOD + col];
                atomicAdd(&u1_all[(size_t)l * DMOD + col], acc2);
            }
        }
        gsync(goB, arr, epoch, tid, blk);

        // ---- stage 4: x1 = LN(u1); u2 += x1 + relu(x1@W1+b1)@W2 + b2; 128 blocks x 16 j ----
        if (blk < 128) {
            float* u1l = u1_all + (size_t)l * DMOD;
            float* u2l = u2_all + (size_t)l * DMOD;
            ln_into(u1l, ln1g + (size_t)l * DMOD, ln1b + (size_t)l * DMOD, xs, red8, tid);
            int j0 = blk * 16;
            int jj = tid & 15, dg = tid >> 4;
            const float* wp = ff1w + (size_t)l * DMOD * FFD + (size_t)(dg * 32) * FFD + j0 + jj;
            float acc = 0.f;
            #pragma unroll
            for (int i = 0; i < 32; ++i) acc += xs[dg * 32 + i] * wp[(size_t)i * FFD];
            redt[tid] = acc;
            __syncthreads();
            for (int off = 128; off >= 16; off >>= 1) {
                if (tid < off) redt[tid] += redt[tid + off];
                __syncthreads();
            }
            if (tid < 16) hs[tid] = fmaxf(redt[tid] + ff1b[(size_t)l * FFD + j0 + tid], 0.f);
            __syncthreads();
            const float* w2p = ff2w + (size_t)l * FFD * DMOD + (size_t)j0 * DMOD;
            #pragma unroll
            for (int half = 0; half < 2; ++half) {
                int col = tid + half * 256;
                float a2 = 0.f;
                #pragma unroll
                for (int j = 0; j < 16; ++j) a2 += hs[j] * w2p[(size_t)j * DMOD + col];
                if (blk == 0) a2 += xs[col] + ff2b[(size_t)l * DMOD + col];
                atomicAdd(&u2l[col], a2);
            }
        }
        gsync(goB, arr, epoch, tid, blk);
    }

    // ---- logits = LN(u2_last) @ pred_w; 256 blocks x 4 cols (+col 1024 on blk 255) ----
    {
        const float* u2L = u2_all + (size_t)(LNUM - 1) * DMOD;
        ln_into(u2L, ln2g + (size_t)(LNUM - 1) * DMOD, ln2b + (size_t)(LNUM - 1) * DMOD, xs, red8, tid);
        int c = tid & 3, dg = tid >> 2;
        int col = blk * 4 + c;
        const float* wp = predw + (size_t)(dg * 8) * VOC + col;
        float acc = 0.f;
        #pragma unroll
        for (int i = 0; i < 8; ++i) acc += xs[dg * 8 + i] * wp[(size_t)i * VOC];
        redt[tid] = acc;
        __syncthreads();
        for (int off = 128; off >= 4; off >>= 1) {
            if (tid < off) redt[tid] += redt[tid + off];
            __syncthreads();
        }
        if (tid < 4) gstoref(&logits[blk * 4 + tid], redt[tid]);
        if (blk == 255) {
            __syncthreads();
            float a2 = xs[tid * 2] * predw[(size_t)(tid * 2) * VOC + 1024]
                     + xs[tid * 2 + 1] * predw[(size_t)(tid * 2 + 1) * VOC + 1024];
            redt[tid] = a2;
            __syncthreads();
            for (int off = 128; off >= 1; off >>= 1) {
                if (tid < off) redt[tid] += redt[tid + off];
                __syncthreads();
            }
            if (tid == 0) gstoref(&logits[1024], redt[0]);
        }
    }
    gsync(goB, arr, epoch, tid, blk);

    // ---- final: penalty + top-15 + softmax + noise argmax; block 0 only ----
    if (blk != 0) return;

    for (int i = tid; i < VOC; i += NTHR) { lg[i] = gloadf(&logits[i]); flagc[i] = 0; }
    __syncthreads();
    for (int j = tid; j < TYN; j += NTHR) flagc[y[j]] = 1;
    __syncthreads();
    for (int i = tid; i < VOC; i += NTHR) {
        if (flagc[i]) { float v = lg[i]; lg[i] = (v < 0.0f) ? v * 1.35f : v / 1.35f; }
    }
    __syncthreads();
    for (int i = tid; i < VOC; i += NTHR) sel[i] = lg[i];
    __syncthreads();

    float v0 = 0.f, v15 = 0.f;
    for (int k = 0; k < 15; ++k) {
        float bv = -INFINITY; int bi = VOC + 1;
        for (int i = tid; i < VOC; i += NTHR) {
            float v = sel[i];
            if (v > bv) { bv = v; bi = i; }
        }
        #pragma unroll
        for (int o = 32; o; o >>= 1) {
            float v2 = __shfl_xor(bv, o, 64);
            int i2 = __shfl_xor(bi, o, 64);
            if (v2 > bv || (v2 == bv && i2 < bi)) { bv = v2; bi = i2; }
        }
        if ((tid & 63) == 0) { rv[tid >> 6] = bv; ri[tid >> 6] = bi; }
        __syncthreads();
        if (tid == 0) {
            for (int w = 1; w < 4; ++w)
                if (rv[w] > rv[0] || (rv[w] == rv[0] && ri[w] < ri[0])) { rv[0] = rv[w]; ri[0] = ri[w]; }
            sel[ri[0]] = -INFINITY;
        }
        __syncthreads();
        if (k == 0)  v0  = rv[0];
        if (k == 14) v15 = rv[0];
        __syncthreads();
    }

    float se = 0.f;
    for (int i = tid; i < VOC; i += NTHR) {
        float v = lg[i];
        if (!(v < v15)) se += expf(v - v0);
    }
    se = wave_red_sum(se);
    if ((tid & 63) == 0) rv[tid >> 6] = se;
    __syncthreads();
    float total = rv[0] + rv[1] + rv[2] + rv[3];
    __syncthreads();

    float bv = -INFINITY; int bi = VOC + 1;
    for (int i = tid; i < VOC; i += NTHR) {
        float v = lg[i];
        float pr = (v < v15) ? 0.0f : expf(v - v0) / total;
        out[i] = pr;
        float r = pr / threefry_normal(i);
        if (r > bv || (r == bv && i < bi)) { bv = r; bi = i; }
    }
    #pragma unroll
    for (int o = 32; o; o >>= 1) {
        float v2 = __shfl_xor(bv, o, 64);
        int i2 = __shfl_xor(bi, o, 64);
        if (v2 > bv || (v2 == bv && i2 < bi)) { bv = v2; bi = i2; }
    }
    __syncthreads();
    if ((tid & 63) == 0) { rv[tid >> 6] = bv; ri[tid >> 6] = bi; }
    __syncthreads();
    if (tid == 0) {
        for (int w = 1; w < 4; ++w)
            if (rv[w] > rv[0] || (rv[w] == rv[0] && ri[w] < ri[0])) { rv[0] = rv[w]; ri[0] = ri[w]; }
        out[VOC] = (float)ri[0];
    }
}

// ---------------- host ----------------

extern "C" void kernel_launch(void* const* d_in, const int* in_sizes, int n_in,
                              void* d_out, int out_size, void* d_ws, size_t ws_size,
                              hipStream_t stream) {
    const int*   y      = (const int*)d_in[0];
    const float* kcache = (const float*)d_in[1];
    const float* vcache = (const float*)d_in[2];
    const float* tokemb = (const float*)d_in[4];
    const float* alpha  = (const float*)d_in[5];
    const float* qkvw   = (const float*)d_in[6];
    const float* qkvb   = (const float*)d_in[7];
    const float* outw   = (const float*)d_in[8];
    const float* outb   = (const float*)d_in[9];
    const float* ln1g   = (const float*)d_in[10];
    const float* ln1b   = (const float*)d_in[11];
    const float* ff1w   = (const float*)d_in[12];
    const float* ff1b   = (const float*)d_in[13];
    const float* ff2w   = (const float*)d_in[14];
    const float* ff2b   = (const float*)d_in[15];
    const float* ln2g   = (const float*)d_in[16];
    const float* ln2b   = (const float*)d_in[17];
    const float* predw  = (const float*)d_in[18];
    float* outp = (float*)d_out;
    float* wsf  = (float*)d_ws;

    // zero: go/arrive slots (8192) + atomic-accumulated qkv/u1/u2 (61440)
    const int ZN = 8192 + LNUM * 3 * DMOD + LNUM * DMOD + LNUM * DMOD;  // 69632
    zero_kernel<<<(ZN + 255) / 256, 256, 0, stream>>>(wsf, ZN);

    void* args[] = {
        (void*)&y, (void*)&kcache, (void*)&vcache, (void*)&tokemb, (void*)&alpha,
        (void*)&qkvw, (void*)&qkvb, (void*)&outw, (void*)&outb,
        (void*)&ln1g, (void*)&ln1b, (void*)&ff1w, (void*)&ff1b,
        (void*)&ff2w, (void*)&ff2b, (void*)&ln2g, (void*)&ln2b,
        (void*)&predw, (void*)&outp, (void*)&wsf
    };
    hipLaunchCooperativeKernel((const void*)decode_kernel, dim3(NBLK), dim3(NTHR),
                               args, 0, stream);
}